// Round 3
// baseline (572.667 us; speedup 1.0000x reference)
//
#include <hip/hip_runtime.h>

#define D 128
#define HB 128    // histogram blocks per role (dst / src)
#define HT 1024   // threads per histogram block

// ---------------------------------------------------------------------------
// Range-ownership histogram (replaces global-atomic count_deg, which was
// memory-side-RMW bound at ~715 GB/s -> 74us). Grid = 2*HB = 256 blocks,
// 1 per CU. Block b owns nodes [b*R, b*R+R); it streams the full index array
// (3.2MB, XCD-L2 resident) and LDS-atomics in-range hits. dst-blocks also
// capture rank[e] (slot within bucket) via ds_add_rtn -> atomic-free CSR fill.
// Zero global atomics; counters fully written by the flush (no memset needed).
// ---------------------------------------------------------------------------
__global__ __launch_bounds__(HT) void hist_kernel(const int* __restrict__ src,
                                                  const int* __restrict__ dst,
                                                  int* __restrict__ cnt_out,
                                                  int* __restrict__ cnt_in,
                                                  int* __restrict__ rank,
                                                  int nE, int nN) {
    __shared__ int lcnt[512];                  // R <= 391 for N=50000
    const int R = (nN + HB - 1) / HB;
    const bool is_dst = (blockIdx.x < HB);
    const int bb = is_dst ? blockIdx.x : (blockIdx.x - HB);
    const int base = bb * R;
    const int t = threadIdx.x;
    for (int i = t; i < R; i += HT) lcnt[i] = 0;
    __syncthreads();

    const int* idx = is_dst ? dst : src;
    const int4* idx4 = (const int4*)idx;
    const int np = nE >> 2;
    if (is_dst) {
        for (int i = t; i < np; i += HT) {
            const int4 v = idx4[i];
            const int e = i * 4;
            unsigned r;
            r = (unsigned)(v.x - base); if (r < (unsigned)R) rank[e]     = atomicAdd(&lcnt[r], 1);
            r = (unsigned)(v.y - base); if (r < (unsigned)R) rank[e + 1] = atomicAdd(&lcnt[r], 1);
            r = (unsigned)(v.z - base); if (r < (unsigned)R) rank[e + 2] = atomicAdd(&lcnt[r], 1);
            r = (unsigned)(v.w - base); if (r < (unsigned)R) rank[e + 3] = atomicAdd(&lcnt[r], 1);
        }
        for (int e = np * 4 + t; e < nE; e += HT) {   // tail (nE % 4)
            unsigned r = (unsigned)(idx[e] - base);
            if (r < (unsigned)R) rank[e] = atomicAdd(&lcnt[r], 1);
        }
    } else {
        for (int i = t; i < np; i += HT) {
            const int4 v = idx4[i];
            unsigned r;
            r = (unsigned)(v.x - base); if (r < (unsigned)R) atomicAdd(&lcnt[r], 1);
            r = (unsigned)(v.y - base); if (r < (unsigned)R) atomicAdd(&lcnt[r], 1);
            r = (unsigned)(v.z - base); if (r < (unsigned)R) atomicAdd(&lcnt[r], 1);
            r = (unsigned)(v.w - base); if (r < (unsigned)R) atomicAdd(&lcnt[r], 1);
        }
        for (int e = np * 4 + t; e < nE; e += HT) {
            unsigned r = (unsigned)(idx[e] - base);
            if (r < (unsigned)R) atomicAdd(&lcnt[r], 1);
        }
    }
    __syncthreads();
    int* g = is_dst ? cnt_in : cnt_out;
    for (int i = t; i < R; i += HT) {
        const int n = base + i;
        if (n < nN) g[n] = lcnt[i];
    }
}

// ---------------------------------------------------------------------------
// Multi-block exclusive scan, stage 1: per-block (1024 elems) scan + block sum.
// ---------------------------------------------------------------------------
__global__ __launch_bounds__(1024) void scan_block_kernel(const int* __restrict__ deg,
                                                          int* __restrict__ rp,
                                                          int* __restrict__ bsum, int n) {
    __shared__ int wsum[16];
    const int t = threadIdx.x;
    const int lane = t & 63;
    const int wid = t >> 6;
    const int i = blockIdx.x * 1024 + t;
    const int v = (i < n) ? deg[i] : 0;
    int s = v;
#pragma unroll
    for (int off = 1; off < 64; off <<= 1) {
        int u = __shfl_up(s, off, 64);
        if (lane >= off) s += u;
    }
    if (lane == 63) wsum[wid] = s;
    __syncthreads();
    if (wid == 0) {
        int ws = (lane < 16) ? wsum[lane] : 0;
#pragma unroll
        for (int off = 1; off < 16; off <<= 1) {
            int u = __shfl_up(ws, off, 64);
            if (lane >= off) ws += u;
        }
        if (lane < 16) wsum[lane] = ws;
    }
    __syncthreads();
    const int excl = s - v + ((wid > 0) ? wsum[wid - 1] : 0);
    if (i < n) rp[i] = excl;
    if (t == 0) bsum[blockIdx.x] = wsum[15];
}

// ---------------------------------------------------------------------------
// Stage 2: one wave scans the block sums (exclusive, in place), writes total.
// ---------------------------------------------------------------------------
__global__ void scan_partials_kernel(int* __restrict__ bsum, int* __restrict__ rp_total, int nb) {
    const int lane = threadIdx.x;  // 64 threads
    int carry = 0;
    for (int base = 0; base < nb; base += 64) {
        const int i = base + lane;
        const int v = (i < nb) ? bsum[i] : 0;
        int s = v;
#pragma unroll
        for (int off = 1; off < 64; off <<= 1) {
            int u = __shfl_up(s, off, 64);
            if (lane >= off) s += u;
        }
        if (i < nb) bsum[i] = s - v + carry;
        carry += __shfl(s, 63, 64);
    }
    if (lane == 0) rp_total[0] = carry;
}

// ---------------------------------------------------------------------------
// Stage 3 (fused with norms): add block offsets, compute rsqrt norms.
// ---------------------------------------------------------------------------
__global__ __launch_bounds__(1024) void finalize_kernel(int* __restrict__ rp,
                                                        const int* __restrict__ bsum,
                                                        const int* __restrict__ cnt_out,
                                                        const int* __restrict__ cnt_in,
                                                        float* __restrict__ onorm,
                                                        float* __restrict__ inorm, int n) {
    const int i = blockIdx.x * 1024 + threadIdx.x;
    if (i < n) {
        rp[i] += bsum[blockIdx.x];
        onorm[i] = rsqrtf(fmaxf((float)cnt_out[i], 1.0f));
        inorm[i] = rsqrtf(fmaxf((float)cnt_in[i], 1.0f));
    }
}

// ---------------------------------------------------------------------------
// Atomic-free CSR fill using captured ranks.
// ---------------------------------------------------------------------------
__global__ void fill_csr_kernel(const int* __restrict__ src, const int* __restrict__ dst,
                                const int* __restrict__ rank, const int* __restrict__ rp,
                                int* __restrict__ srcs_sorted, int nE) {
    int e = blockIdx.x * 256 + threadIdx.x;
    if (e < nE) {
        srcs_sorted[rp[dst[e]] + rank[e]] = src[e];
    }
}

// ---------------------------------------------------------------------------
// Aggregation: agg[n,:] = sum_{e: dst==n} x[src_e,:] (* onorm[src_e] if SCALE)
// 32 threads/node, unroll-4 with 4 accumulators for outstanding-load MLP.
// ---------------------------------------------------------------------------
template <bool SCALE>
__global__ __launch_bounds__(256) void aggregate_kernel(const float* __restrict__ x,
                                                        const float* __restrict__ onorm,
                                                        const int* __restrict__ rp,
                                                        const int* __restrict__ srcs,
                                                        float* __restrict__ agg, int n_nodes) {
    const int node = blockIdx.x * 8 + (threadIdx.x >> 5);
    const int lane = threadIdx.x & 31;
    if (node >= n_nodes) return;
    const int e0 = rp[node];
    const int e1 = rp[node + 1];
    const float4* __restrict__ x4 = (const float4*)x;
    float4 a0 = make_float4(0.f, 0.f, 0.f, 0.f);
    float4 a1 = make_float4(0.f, 0.f, 0.f, 0.f);
    float4 a2 = make_float4(0.f, 0.f, 0.f, 0.f);
    float4 a3 = make_float4(0.f, 0.f, 0.f, 0.f);
    int e = e0;
    for (; e + 4 <= e1; e += 4) {
        const int s0 = srcs[e], s1 = srcs[e + 1], s2 = srcs[e + 2], s3 = srcs[e + 3];
        const float4 v0 = x4[(size_t)s0 * 32 + lane];
        const float4 v1 = x4[(size_t)s1 * 32 + lane];
        const float4 v2 = x4[(size_t)s2 * 32 + lane];
        const float4 v3 = x4[(size_t)s3 * 32 + lane];
        if (SCALE) {
            const float n0 = onorm[s0], n1 = onorm[s1], n2 = onorm[s2], n3 = onorm[s3];
            a0.x = fmaf(v0.x, n0, a0.x); a0.y = fmaf(v0.y, n0, a0.y);
            a0.z = fmaf(v0.z, n0, a0.z); a0.w = fmaf(v0.w, n0, a0.w);
            a1.x = fmaf(v1.x, n1, a1.x); a1.y = fmaf(v1.y, n1, a1.y);
            a1.z = fmaf(v1.z, n1, a1.z); a1.w = fmaf(v1.w, n1, a1.w);
            a2.x = fmaf(v2.x, n2, a2.x); a2.y = fmaf(v2.y, n2, a2.y);
            a2.z = fmaf(v2.z, n2, a2.z); a2.w = fmaf(v2.w, n2, a2.w);
            a3.x = fmaf(v3.x, n3, a3.x); a3.y = fmaf(v3.y, n3, a3.y);
            a3.z = fmaf(v3.z, n3, a3.z); a3.w = fmaf(v3.w, n3, a3.w);
        } else {
            a0.x += v0.x; a0.y += v0.y; a0.z += v0.z; a0.w += v0.w;
            a1.x += v1.x; a1.y += v1.y; a1.z += v1.z; a1.w += v1.w;
            a2.x += v2.x; a2.y += v2.y; a2.z += v2.z; a2.w += v2.w;
            a3.x += v3.x; a3.y += v3.y; a3.z += v3.z; a3.w += v3.w;
        }
    }
    for (; e < e1; ++e) {
        const int s0 = srcs[e];
        const float4 v0 = x4[(size_t)s0 * 32 + lane];
        if (SCALE) {
            const float n0 = onorm[s0];
            a0.x = fmaf(v0.x, n0, a0.x); a0.y = fmaf(v0.y, n0, a0.y);
            a0.z = fmaf(v0.z, n0, a0.z); a0.w = fmaf(v0.w, n0, a0.w);
        } else {
            a0.x += v0.x; a0.y += v0.y; a0.z += v0.z; a0.w += v0.w;
        }
    }
    a0.x += a1.x + a2.x + a3.x;
    a0.y += a1.y + a2.y + a3.y;
    a0.z += a1.z + a2.z + a3.z;
    a0.w += a1.w + a2.w + a3.w;
    ((float4*)(agg + (size_t)node * D))[lane] = a0;
}

// ---------------------------------------------------------------------------
// GEMM + epilogue, NO-LDS version. Rationale (R2 model): the LDS variant was
// issue-bound on ds_read_b128 (4 waves x 16 reads x 12cyc = 768 > 512 VALU
// cyc per k4-iter) and its 130KB LDS capped occupancy at 1 block/CU.
// Here A and W are read straight from global: a4 loads are 16-lane broadcasts
// (4 distinct lines/instr, L1-hit for 3 of 4 consecutive k4), W rows are hot
// in L1/L2 across all blocks. No barrier, ~130 VGPR -> 3 blocks/CU.
// out[n,c] = post((sum_k A[n,k]*W[k,c]) * inorm[n] + b[c]);
// post = relu (RELU), then * onorm[n] (OSCALE, pre-scales next layer's input).
// ---------------------------------------------------------------------------
template <bool RELU, bool OSCALE>
__global__ __launch_bounds__(256) void gemm_epi_kernel(const float* __restrict__ A,
                                                       const float* __restrict__ W,
                                                       const float* __restrict__ b,
                                                       const float* __restrict__ inorm,
                                                       const float* __restrict__ onorm,
                                                       float* __restrict__ out, int nrows) {
    const int t = threadIdx.x;
    const int tc = t & 15;    // 16 col-groups of 8 cols
    const int tr = t >> 4;    // 16 row-groups of 8 rows
    const int row0 = blockIdx.x * 128;
    const int rows = min(128, nrows - row0);

    float acc[8][8];
#pragma unroll
    for (int i = 0; i < 8; ++i)
#pragma unroll
        for (int j = 0; j < 8; ++j) acc[i][j] = 0.f;

    const float* Ap = A + (size_t)(row0 + tr * 8) * D;
    const float* Wp = W + tc * 8;

#pragma unroll 2
    for (int k4 = 0; k4 < 32; ++k4) {
        float4 a4[8];
#pragma unroll
        for (int i = 0; i < 8; ++i)
            a4[i] = *(const float4*)(Ap + (size_t)i * D + k4 * 4);
#pragma unroll
        for (int kk = 0; kk < 4; ++kk) {
            const float4 wlo = *(const float4*)(Wp + (k4 * 4 + kk) * D);
            const float4 whi = *(const float4*)(Wp + (k4 * 4 + kk) * D + 4);
#pragma unroll
            for (int i = 0; i < 8; ++i) {
                const float av = ((const float*)&a4[i])[kk];
                acc[i][0] = fmaf(av, wlo.x, acc[i][0]);
                acc[i][1] = fmaf(av, wlo.y, acc[i][1]);
                acc[i][2] = fmaf(av, wlo.z, acc[i][2]);
                acc[i][3] = fmaf(av, wlo.w, acc[i][3]);
                acc[i][4] = fmaf(av, whi.x, acc[i][4]);
                acc[i][5] = fmaf(av, whi.y, acc[i][5]);
                acc[i][6] = fmaf(av, whi.z, acc[i][6]);
                acc[i][7] = fmaf(av, whi.w, acc[i][7]);
            }
        }
    }

    const float4 bv0 = *(const float4*)&b[tc * 8];
    const float4 bv1 = *(const float4*)&b[tc * 8 + 4];
#pragma unroll
    for (int i = 0; i < 8; ++i) {
        const int r = tr * 8 + i;
        if (r < rows) {
            const float nm = inorm[row0 + r];
            float4 o0, o1;
            o0.x = fmaf(acc[i][0], nm, bv0.x); o0.y = fmaf(acc[i][1], nm, bv0.y);
            o0.z = fmaf(acc[i][2], nm, bv0.z); o0.w = fmaf(acc[i][3], nm, bv0.w);
            o1.x = fmaf(acc[i][4], nm, bv1.x); o1.y = fmaf(acc[i][5], nm, bv1.y);
            o1.z = fmaf(acc[i][6], nm, bv1.z); o1.w = fmaf(acc[i][7], nm, bv1.w);
            if (RELU) {
                o0.x = fmaxf(o0.x, 0.f); o0.y = fmaxf(o0.y, 0.f);
                o0.z = fmaxf(o0.z, 0.f); o0.w = fmaxf(o0.w, 0.f);
                o1.x = fmaxf(o1.x, 0.f); o1.y = fmaxf(o1.y, 0.f);
                o1.z = fmaxf(o1.z, 0.f); o1.w = fmaxf(o1.w, 0.f);
            }
            if (OSCALE) {
                const float os = onorm[row0 + r];
                o0.x *= os; o0.y *= os; o0.z *= os; o0.w *= os;
                o1.x *= os; o1.y *= os; o1.z *= os; o1.w *= os;
            }
            float* op = &out[(size_t)(row0 + r) * D + tc * 8];
            *(float4*)op = o0;
            *(float4*)(op + 4) = o1;
        }
    }
}

// ---------------------------------------------------------------------------
// Host launch
// ---------------------------------------------------------------------------
extern "C" void kernel_launch(void* const* d_in, const int* in_sizes, int n_in,
                              void* d_out, int out_size, void* d_ws, size_t ws_size,
                              hipStream_t stream) {
    const float* x   = (const float*)d_in[0];
    const int*   src = (const int*)d_in[1];
    const int*   dst = (const int*)d_in[2];
    const float* W1  = (const float*)d_in[3];
    const float* b1  = (const float*)d_in[4];
    const float* W2  = (const float*)d_in[5];
    const float* b2  = (const float*)d_in[6];
    const float* W3  = (const float*)d_in[7];
    const float* b3  = (const float*)d_in[8];

    const int N = in_sizes[0] / D;   // 50000
    const int E = in_sizes[1];       // 800000

    char* p = (char*)d_ws;
    auto alloc = [&](size_t bytes) -> void* {
        void* r = (void*)p;
        p += (bytes + 255) & ~(size_t)255;
        return r;
    };
    int*   cnt_out = (int*)alloc((size_t)N * 4);
    int*   cnt_in  = (int*)alloc((size_t)N * 4);
    int*   rp      = (int*)alloc((size_t)(N + 1) * 4);
    int*   rank    = (int*)alloc((size_t)E * 4);
    int*   bsum    = (int*)alloc(1024 * 4);
    float* onorm   = (float*)alloc((size_t)N * 4);
    float* inorm   = (float*)alloc((size_t)N * 4);
    int*   srcs    = (int*)alloc((size_t)E * 4);
    float* bufA    = (float*)alloc((size_t)N * D * 4);
    float* bufB    = (float*)alloc((size_t)N * D * 4);
    float* outf    = (float*)d_out;

    const int nb = (N + 1023) / 1024;  // 49 scan blocks
    hist_kernel<<<2 * HB, HT, 0, stream>>>(src, dst, cnt_out, cnt_in, rank, E, N);
    scan_block_kernel<<<nb, 1024, 0, stream>>>(cnt_in, rp, bsum, N);
    scan_partials_kernel<<<1, 64, 0, stream>>>(bsum, &rp[N], nb);
    finalize_kernel<<<nb, 1024, 0, stream>>>(rp, bsum, cnt_out, cnt_in, onorm, inorm, N);
    fill_csr_kernel<<<(E + 255) / 256, 256, 0, stream>>>(src, dst, rank, rp, srcs, E);

    const int aggGrid = (N + 7) / 8;
    const int gemmGrid = (N + 127) / 128;

    // Layer 1: per-edge onorm scaling (x is unscaled input)
    aggregate_kernel<true><<<aggGrid, 256, 0, stream>>>(x, onorm, rp, srcs, bufA, N);
    gemm_epi_kernel<true, true><<<gemmGrid, 256, 0, stream>>>(bufA, W1, b1, inorm, onorm, bufB, N);
    // Layer 2: bufB already carries onorm scaling from the epilogue
    aggregate_kernel<false><<<aggGrid, 256, 0, stream>>>(bufB, onorm, rp, srcs, bufA, N);
    gemm_epi_kernel<true, true><<<gemmGrid, 256, 0, stream>>>(bufA, W2, b2, inorm, onorm, bufB, N);
    // Layer 3: plain epilogue straight to d_out
    aggregate_kernel<false><<<aggGrid, 256, 0, stream>>>(bufB, onorm, rp, srcs, bufA, N);
    gemm_epi_kernel<false, false><<<gemmGrid, 256, 0, stream>>>(bufA, W3, b3, inorm, onorm, outf, N);
}

// Round 4
// 506.388 us; speedup vs baseline: 1.1309x; 1.1309x over previous
//
#include <hip/hip_runtime.h>

#define D 128

// ---------------------------------------------------------------------------
// FUSED: raw GEMM1 (y1 = x @ W1, no epilogue) + degree count + rank capture.
// Rationale: count_deg is memory-side-atomic-bound (52.9MB RMW, VALUBusy 0.3%,
// 74us in R2) — its VALU/CU capacity is idle. GEMM1 is graph-independent
// (linearity lets the W1 transform commute past the gather), so its VALU work
// runs concurrently on the same CUs. No LDS in either path so count blocks
// stay fully resident. R3's range-hist (100us) proved worse than atomics.
// ---------------------------------------------------------------------------
__global__ __launch_bounds__(256) void fused_gemm1_count_kernel(
    const float* __restrict__ x, const float* __restrict__ W1,
    const int* __restrict__ src, const int* __restrict__ dst,
    int* __restrict__ cnt_out, int* __restrict__ cnt_in, int* __restrict__ rank,
    float* __restrict__ y1, int nrows, int nE, int nGemmBlocks) {
    const int t = threadIdx.x;
    if ((int)blockIdx.x >= nGemmBlocks) {
        // ---- count path: 1 edge/thread, 2 global atomics + rank store ----
        const int e = (blockIdx.x - nGemmBlocks) * 256 + t;
        if (e < nE) {
            atomicAdd(&cnt_out[src[e]], 1);
            rank[e] = atomicAdd(&cnt_in[dst[e]], 1);
        }
        return;
    }
    // ---- GEMM path: 128x128 tile, 8x8 micro-tile, A/W straight from global ----
    const int tc = t & 15;
    const int tr = t >> 4;
    const int row0 = blockIdx.x * 128;
    const int rows = min(128, nrows - row0);

    float acc[8][8];
#pragma unroll
    for (int i = 0; i < 8; ++i)
#pragma unroll
        for (int j = 0; j < 8; ++j) acc[i][j] = 0.f;

    const float* Ap = x + (size_t)(row0 + tr * 8) * D;
    const float* Wp = W1 + tc * 8;

#pragma unroll 2
    for (int k4 = 0; k4 < 32; ++k4) {
        float4 a4[8];
#pragma unroll
        for (int i = 0; i < 8; ++i)
            a4[i] = *(const float4*)(Ap + (size_t)i * D + k4 * 4);
#pragma unroll
        for (int kk = 0; kk < 4; ++kk) {
            const float4 wlo = *(const float4*)(Wp + (k4 * 4 + kk) * D);
            const float4 whi = *(const float4*)(Wp + (k4 * 4 + kk) * D + 4);
#pragma unroll
            for (int i = 0; i < 8; ++i) {
                const float av = ((const float*)&a4[i])[kk];
                acc[i][0] = fmaf(av, wlo.x, acc[i][0]);
                acc[i][1] = fmaf(av, wlo.y, acc[i][1]);
                acc[i][2] = fmaf(av, wlo.z, acc[i][2]);
                acc[i][3] = fmaf(av, wlo.w, acc[i][3]);
                acc[i][4] = fmaf(av, whi.x, acc[i][4]);
                acc[i][5] = fmaf(av, whi.y, acc[i][5]);
                acc[i][6] = fmaf(av, whi.z, acc[i][6]);
                acc[i][7] = fmaf(av, whi.w, acc[i][7]);
            }
        }
    }
#pragma unroll
    for (int i = 0; i < 8; ++i) {
        const int r = tr * 8 + i;
        if (r < rows) {
            float* op = &y1[(size_t)(row0 + r) * D + tc * 8];
            *(float4*)op = make_float4(acc[i][0], acc[i][1], acc[i][2], acc[i][3]);
            *(float4*)(op + 4) = make_float4(acc[i][4], acc[i][5], acc[i][6], acc[i][7]);
        }
    }
}

// ---------------------------------------------------------------------------
// Multi-block exclusive scan, stage 1.
// ---------------------------------------------------------------------------
__global__ __launch_bounds__(1024) void scan_block_kernel(const int* __restrict__ deg,
                                                          int* __restrict__ rp,
                                                          int* __restrict__ bsum, int n) {
    __shared__ int wsum[16];
    const int t = threadIdx.x;
    const int lane = t & 63;
    const int wid = t >> 6;
    const int i = blockIdx.x * 1024 + t;
    const int v = (i < n) ? deg[i] : 0;
    int s = v;
#pragma unroll
    for (int off = 1; off < 64; off <<= 1) {
        int u = __shfl_up(s, off, 64);
        if (lane >= off) s += u;
    }
    if (lane == 63) wsum[wid] = s;
    __syncthreads();
    if (wid == 0) {
        int ws = (lane < 16) ? wsum[lane] : 0;
#pragma unroll
        for (int off = 1; off < 16; off <<= 1) {
            int u = __shfl_up(ws, off, 64);
            if (lane >= off) ws += u;
        }
        if (lane < 16) wsum[lane] = ws;
    }
    __syncthreads();
    const int excl = s - v + ((wid > 0) ? wsum[wid - 1] : 0);
    if (i < n) rp[i] = excl;
    if (t == 0) bsum[blockIdx.x] = wsum[15];
}

// ---------------------------------------------------------------------------
// Stage 2: one wave scans block sums in place.
// ---------------------------------------------------------------------------
__global__ void scan_partials_kernel(int* __restrict__ bsum, int* __restrict__ rp_total, int nb) {
    const int lane = threadIdx.x;  // 64
    int carry = 0;
    for (int base = 0; base < nb; base += 64) {
        const int i = base + lane;
        const int v = (i < nb) ? bsum[i] : 0;
        int s = v;
#pragma unroll
        for (int off = 1; off < 64; off <<= 1) {
            int u = __shfl_up(s, off, 64);
            if (lane >= off) s += u;
        }
        if (i < nb) bsum[i] = s - v + carry;
        carry += __shfl(s, 63, 64);
    }
    if (lane == 0) rp_total[0] = carry;
}

// ---------------------------------------------------------------------------
// Stage 3: add block offsets + rsqrt norms.
// ---------------------------------------------------------------------------
__global__ __launch_bounds__(1024) void finalize_kernel(int* __restrict__ rp,
                                                        const int* __restrict__ bsum,
                                                        const int* __restrict__ cnt_out,
                                                        const int* __restrict__ cnt_in,
                                                        float* __restrict__ onorm,
                                                        float* __restrict__ inorm, int n) {
    const int i = blockIdx.x * 1024 + threadIdx.x;
    if (i < n) {
        rp[i] += bsum[blockIdx.x];
        onorm[i] = rsqrtf(fmaxf((float)cnt_out[i], 1.0f));
        inorm[i] = rsqrtf(fmaxf((float)cnt_in[i], 1.0f));
    }
}

// ---------------------------------------------------------------------------
// Atomic-free CSR fill using captured ranks.
// ---------------------------------------------------------------------------
__global__ void fill_csr_kernel(const int* __restrict__ src, const int* __restrict__ dst,
                                const int* __restrict__ rank, const int* __restrict__ rp,
                                int* __restrict__ srcs_sorted, int nE) {
    int e = blockIdx.x * 256 + threadIdx.x;
    if (e < nE) {
        srcs_sorted[rp[dst[e]] + rank[e]] = src[e];
    }
}

// ---------------------------------------------------------------------------
// Aggregation: r[n] = sum_{e: dst==n} x[src_e] (* onorm[src_e] if SCALE)
// EPI: out[n] = relu(r*inorm[n] + b) * onorm[n]  (layer-1 epilogue, fused here
// because GEMM1 ran raw inside the count dispatch).
// Unroll-8: grouped index loads then 8 row-gathers in flight per node-group
// (deeper MLP against L2/L3 gather latency).
// ---------------------------------------------------------------------------
template <bool SCALE, bool EPI>
__global__ __launch_bounds__(256) void aggregate_kernel(const float* __restrict__ x,
                                                        const float* __restrict__ onorm,
                                                        const float* __restrict__ inorm,
                                                        const float* __restrict__ bias,
                                                        const int* __restrict__ rp,
                                                        const int* __restrict__ srcs,
                                                        float* __restrict__ agg, int n_nodes) {
    const int node = blockIdx.x * 8 + (threadIdx.x >> 5);
    const int lane = threadIdx.x & 31;
    if (node >= n_nodes) return;
    const int e0 = rp[node];
    const int e1 = rp[node + 1];
    const float4* __restrict__ x4 = (const float4*)x;
    float4 a[4];
#pragma unroll
    for (int j = 0; j < 4; ++j) a[j] = make_float4(0.f, 0.f, 0.f, 0.f);

    int e = e0;
    for (; e + 8 <= e1; e += 8) {
        int s[8];
#pragma unroll
        for (int j = 0; j < 8; ++j) s[j] = srcs[e + j];
        float4 v[8];
#pragma unroll
        for (int j = 0; j < 8; ++j) v[j] = x4[(size_t)s[j] * 32 + lane];
        if (SCALE) {
            float nm[8];
#pragma unroll
            for (int j = 0; j < 8; ++j) nm[j] = onorm[s[j]];
#pragma unroll
            for (int j = 0; j < 8; ++j) {
                float4& acc = a[j & 3];
                acc.x = fmaf(v[j].x, nm[j], acc.x);
                acc.y = fmaf(v[j].y, nm[j], acc.y);
                acc.z = fmaf(v[j].z, nm[j], acc.z);
                acc.w = fmaf(v[j].w, nm[j], acc.w);
            }
        } else {
#pragma unroll
            for (int j = 0; j < 8; ++j) {
                float4& acc = a[j & 3];
                acc.x += v[j].x; acc.y += v[j].y; acc.z += v[j].z; acc.w += v[j].w;
            }
        }
    }
    for (; e < e1; ++e) {
        const int s0 = srcs[e];
        const float4 v0 = x4[(size_t)s0 * 32 + lane];
        if (SCALE) {
            const float n0 = onorm[s0];
            a[0].x = fmaf(v0.x, n0, a[0].x); a[0].y = fmaf(v0.y, n0, a[0].y);
            a[0].z = fmaf(v0.z, n0, a[0].z); a[0].w = fmaf(v0.w, n0, a[0].w);
        } else {
            a[0].x += v0.x; a[0].y += v0.y; a[0].z += v0.z; a[0].w += v0.w;
        }
    }
    float4 r;
    r.x = a[0].x + a[1].x + a[2].x + a[3].x;
    r.y = a[0].y + a[1].y + a[2].y + a[3].y;
    r.z = a[0].z + a[1].z + a[2].z + a[3].z;
    r.w = a[0].w + a[1].w + a[2].w + a[3].w;
    if (EPI) {
        const float inm = inorm[node];
        const float onm = onorm[node];
        const float4 bv = ((const float4*)bias)[lane];
        r.x = fmaxf(fmaf(r.x, inm, bv.x), 0.f) * onm;
        r.y = fmaxf(fmaf(r.y, inm, bv.y), 0.f) * onm;
        r.z = fmaxf(fmaf(r.z, inm, bv.z), 0.f) * onm;
        r.w = fmaxf(fmaf(r.w, inm, bv.w), 0.f) * onm;
    }
    ((float4*)(agg + (size_t)node * D))[lane] = r;
}

// ---------------------------------------------------------------------------
// LDS GEMM + epilogue (R2-proven config; R3's no-LDS total regressed ~50us).
// out[n,c] = post((sum_k A[n,k]*W[k,c]) * inorm[n] + b[c]);
// post = relu (RELU), then * onorm[n] (OSCALE).
// ---------------------------------------------------------------------------
template <bool RELU, bool OSCALE>
__global__ __launch_bounds__(256) void gemm_epi_kernel(const float* __restrict__ A,
                                                       const float* __restrict__ W,
                                                       const float* __restrict__ b,
                                                       const float* __restrict__ inorm,
                                                       const float* __restrict__ onorm,
                                                       float* __restrict__ out, int nrows) {
    __shared__ float sW[D * D];        // 64 KB
    __shared__ float sA[128 * 132];    // 66 KB
    const int t = threadIdx.x;
    const int tc = t & 15;
    const int tr = t >> 4;

    for (int i = t; i < D * D / 4; i += 256)
        ((float4*)sW)[i] = ((const float4*)W)[i];

    const int row0 = blockIdx.x * 128;
    const int rows = min(128, nrows - row0);

    for (int i = t; i < rows * 32; i += 256) {
        const int r = i >> 5;
        const int k4 = i & 31;
        *(float4*)&sA[r * 132 + k4 * 4] = ((const float4*)(A + (size_t)(row0 + r) * D))[k4];
    }
    __syncthreads();

    float acc[8][8];
#pragma unroll
    for (int i = 0; i < 8; ++i)
#pragma unroll
        for (int j = 0; j < 8; ++j) acc[i][j] = 0.f;

    for (int k4 = 0; k4 < 32; ++k4) {
        float4 a4[8];
#pragma unroll
        for (int i = 0; i < 8; ++i)
            a4[i] = *(const float4*)&sA[(tr * 8 + i) * 132 + k4 * 4];
#pragma unroll
        for (int kk = 0; kk < 4; ++kk) {
            const float4 wlo = *(const float4*)&sW[(k4 * 4 + kk) * D + tc * 8];
            const float4 whi = *(const float4*)&sW[(k4 * 4 + kk) * D + tc * 8 + 4];
#pragma unroll
            for (int i = 0; i < 8; ++i) {
                const float av = ((const float*)&a4[i])[kk];
                acc[i][0] = fmaf(av, wlo.x, acc[i][0]);
                acc[i][1] = fmaf(av, wlo.y, acc[i][1]);
                acc[i][2] = fmaf(av, wlo.z, acc[i][2]);
                acc[i][3] = fmaf(av, wlo.w, acc[i][3]);
                acc[i][4] = fmaf(av, whi.x, acc[i][4]);
                acc[i][5] = fmaf(av, whi.y, acc[i][5]);
                acc[i][6] = fmaf(av, whi.z, acc[i][6]);
                acc[i][7] = fmaf(av, whi.w, acc[i][7]);
            }
        }
    }

    const float4 bv0 = *(const float4*)&b[tc * 8];
    const float4 bv1 = *(const float4*)&b[tc * 8 + 4];
#pragma unroll
    for (int i = 0; i < 8; ++i) {
        const int r = tr * 8 + i;
        if (r < rows) {
            const float nm = inorm[row0 + r];
            float4 o0, o1;
            o0.x = fmaf(acc[i][0], nm, bv0.x); o0.y = fmaf(acc[i][1], nm, bv0.y);
            o0.z = fmaf(acc[i][2], nm, bv0.z); o0.w = fmaf(acc[i][3], nm, bv0.w);
            o1.x = fmaf(acc[i][4], nm, bv1.x); o1.y = fmaf(acc[i][5], nm, bv1.y);
            o1.z = fmaf(acc[i][6], nm, bv1.z); o1.w = fmaf(acc[i][7], nm, bv1.w);
            if (RELU) {
                o0.x = fmaxf(o0.x, 0.f); o0.y = fmaxf(o0.y, 0.f);
                o0.z = fmaxf(o0.z, 0.f); o0.w = fmaxf(o0.w, 0.f);
                o1.x = fmaxf(o1.x, 0.f); o1.y = fmaxf(o1.y, 0.f);
                o1.z = fmaxf(o1.z, 0.f); o1.w = fmaxf(o1.w, 0.f);
            }
            if (OSCALE) {
                const float os = onorm[row0 + r];
                o0.x *= os; o0.y *= os; o0.z *= os; o0.w *= os;
                o1.x *= os; o1.y *= os; o1.z *= os; o1.w *= os;
            }
            float* op = &out[(size_t)(row0 + r) * D + tc * 8];
            *(float4*)op = o0;
            *(float4*)(op + 4) = o1;
        }
    }
}

// ---------------------------------------------------------------------------
// Host launch
// ---------------------------------------------------------------------------
extern "C" void kernel_launch(void* const* d_in, const int* in_sizes, int n_in,
                              void* d_out, int out_size, void* d_ws, size_t ws_size,
                              hipStream_t stream) {
    const float* x   = (const float*)d_in[0];
    const int*   src = (const int*)d_in[1];
    const int*   dst = (const int*)d_in[2];
    const float* W1  = (const float*)d_in[3];
    const float* b1  = (const float*)d_in[4];
    const float* W2  = (const float*)d_in[5];
    const float* b2  = (const float*)d_in[6];
    const float* W3  = (const float*)d_in[7];
    const float* b3  = (const float*)d_in[8];

    const int N = in_sizes[0] / D;   // 50000
    const int E = in_sizes[1];       // 800000

    char* p = (char*)d_ws;
    auto alloc = [&](size_t bytes) -> void* {
        void* r = (void*)p;
        p += (bytes + 255) & ~(size_t)255;
        return r;
    };
    int*   cnt_out = (int*)alloc((size_t)N * 4);
    int*   cnt_in  = (int*)alloc((size_t)N * 4);
    int*   rp      = (int*)alloc((size_t)(N + 1) * 4);
    int*   rank    = (int*)alloc((size_t)E * 4);
    int*   bsum    = (int*)alloc(1024 * 4);
    float* onorm   = (float*)alloc((size_t)N * 4);
    float* inorm   = (float*)alloc((size_t)N * 4);
    int*   srcs    = (int*)alloc((size_t)E * 4);
    float* bufA    = (float*)alloc((size_t)N * D * 4);
    float* bufB    = (float*)alloc((size_t)N * D * 4);
    float* outf    = (float*)d_out;

    // Zero the counters (adjacent carve -> one memset)
    hipMemsetAsync(cnt_out, 0, (size_t)((char*)cnt_in - (char*)cnt_out) + (size_t)N * 4, stream);

    const int nb = (N + 1023) / 1024;
    const int gemmGrid = (N + 127) / 128;      // 391
    const int countGrid = (E + 255) / 256;     // 3125
    const int aggGrid = (N + 7) / 8;

    // Phase 0: y1 = x@W1 (raw) overlapped with degree count + rank capture
    fused_gemm1_count_kernel<<<gemmGrid + countGrid, 256, 0, stream>>>(
        x, W1, src, dst, cnt_out, cnt_in, rank, bufA, N, E, gemmGrid);
    scan_block_kernel<<<nb, 1024, 0, stream>>>(cnt_in, rp, bsum, N);
    scan_partials_kernel<<<1, 64, 0, stream>>>(bsum, &rp[N], nb);
    finalize_kernel<<<nb, 1024, 0, stream>>>(rp, bsum, cnt_out, cnt_in, onorm, inorm, N);
    fill_csr_kernel<<<countGrid, 256, 0, stream>>>(src, dst, rank, rp, srcs, E);

    // Layer 1: aggregate y1 with per-edge onorm scale + fused epilogue -> bufB
    aggregate_kernel<true, true><<<aggGrid, 256, 0, stream>>>(
        bufA, onorm, inorm, b1, rp, srcs, bufB, N);
    // Layer 2: plain aggregate (bufB pre-scaled), GEMM+epi -> bufB
    aggregate_kernel<false, false><<<aggGrid, 256, 0, stream>>>(
        bufB, onorm, inorm, b2, rp, srcs, bufA, N);
    gemm_epi_kernel<true, true><<<gemmGrid, 256, 0, stream>>>(bufA, W2, b2, inorm, onorm, bufB, N);
    // Layer 3: plain aggregate, GEMM+epi (no relu/prescale) -> d_out
    aggregate_kernel<false, false><<<aggGrid, 256, 0, stream>>>(
        bufB, onorm, inorm, b3, rp, srcs, bufA, N);
    gemm_epi_kernel<false, false><<<gemmGrid, 256, 0, stream>>>(bufA, W3, b3, inorm, onorm, outf, N);
}

// Round 5
// 489.786 us; speedup vs baseline: 1.1692x; 1.0339x over previous
//
#include <hip/hip_runtime.h>

#define D 128

// ---------------------------------------------------------------------------
// Degree counting + rank capture (standalone — R4 proved fusing GEMM work in
// starves the atomic pipeline of resident waves: 139us fused vs 74us alone.
// Atomic throughput ~ resident count-waves; keep this kernel pure).
// ---------------------------------------------------------------------------
__global__ void count_deg_kernel(const int* __restrict__ src, const int* __restrict__ dst,
                                 int* __restrict__ cnt_out, int* __restrict__ cnt_in,
                                 int* __restrict__ rank, int nE) {
    int e = blockIdx.x * 256 + threadIdx.x;
    if (e < nE) {
        atomicAdd(&cnt_out[src[e]], 1);
        rank[e] = atomicAdd(&cnt_in[dst[e]], 1);
    }
}

// ---------------------------------------------------------------------------
// Multi-block exclusive scan, stage 1.
// ---------------------------------------------------------------------------
__global__ __launch_bounds__(1024) void scan_block_kernel(const int* __restrict__ deg,
                                                          int* __restrict__ rp,
                                                          int* __restrict__ bsum, int n) {
    __shared__ int wsum[16];
    const int t = threadIdx.x;
    const int lane = t & 63;
    const int wid = t >> 6;
    const int i = blockIdx.x * 1024 + t;
    const int v = (i < n) ? deg[i] : 0;
    int s = v;
#pragma unroll
    for (int off = 1; off < 64; off <<= 1) {
        int u = __shfl_up(s, off, 64);
        if (lane >= off) s += u;
    }
    if (lane == 63) wsum[wid] = s;
    __syncthreads();
    if (wid == 0) {
        int ws = (lane < 16) ? wsum[lane] : 0;
#pragma unroll
        for (int off = 1; off < 16; off <<= 1) {
            int u = __shfl_up(ws, off, 64);
            if (lane >= off) ws += u;
        }
        if (lane < 16) wsum[lane] = ws;
    }
    __syncthreads();
    const int excl = s - v + ((wid > 0) ? wsum[wid - 1] : 0);
    if (i < n) rp[i] = excl;
    if (t == 0) bsum[blockIdx.x] = wsum[15];
}

// ---------------------------------------------------------------------------
// Stage 2: one wave scans block sums in place.
// ---------------------------------------------------------------------------
__global__ void scan_partials_kernel(int* __restrict__ bsum, int* __restrict__ rp_total, int nb) {
    const int lane = threadIdx.x;  // 64
    int carry = 0;
    for (int base = 0; base < nb; base += 64) {
        const int i = base + lane;
        const int v = (i < nb) ? bsum[i] : 0;
        int s = v;
#pragma unroll
        for (int off = 1; off < 64; off <<= 1) {
            int u = __shfl_up(s, off, 64);
            if (lane >= off) s += u;
        }
        if (i < nb) bsum[i] = s - v + carry;
        carry += __shfl(s, 63, 64);
    }
    if (lane == 0) rp_total[0] = carry;
}

// ---------------------------------------------------------------------------
// Stage 3: add block offsets + rsqrt norms.
// ---------------------------------------------------------------------------
__global__ __launch_bounds__(1024) void finalize_kernel(int* __restrict__ rp,
                                                        const int* __restrict__ bsum,
                                                        const int* __restrict__ cnt_out,
                                                        const int* __restrict__ cnt_in,
                                                        float* __restrict__ onorm,
                                                        float* __restrict__ inorm, int n) {
    const int i = blockIdx.x * 1024 + threadIdx.x;
    if (i < n) {
        rp[i] += bsum[blockIdx.x];
        onorm[i] = rsqrtf(fmaxf((float)cnt_out[i], 1.0f));
        inorm[i] = rsqrtf(fmaxf((float)cnt_in[i], 1.0f));
    }
}

// ---------------------------------------------------------------------------
// Atomic-free CSR fill using captured ranks.
// ---------------------------------------------------------------------------
__global__ void fill_csr_kernel(const int* __restrict__ src, const int* __restrict__ dst,
                                const int* __restrict__ rank, const int* __restrict__ rp,
                                int* __restrict__ srcs_sorted, int nE) {
    int e = blockIdx.x * 256 + threadIdx.x;
    if (e < nE) {
        srcs_sorted[rp[dst[e]] + rank[e]] = src[e];
    }
}

// ---------------------------------------------------------------------------
// Aggregation, wave-per-node: agg[n,:] = sum_{e: dst==n} x[src_e,:]
// (inputs are always pre-scaled by onorm — GEMM epilogues handle it — so the
// inner loop is a pure gather-sum with NO per-edge norm load).
// Lane layout: eh=lane>>5 picks one of 2 edges per load instr, c4=lane&31 is
// the float4 column. Both wave halves share one edge list -> zero trip-count
// divergence (old version straddled 2 nodes per wave). Main loop keeps 8
// edges (4 KB) in flight; halves merge with one shfl_xor(32) at the end.
// EPI (layer 1): out = relu(r*inorm[n] + b)*onorm[n].
// ---------------------------------------------------------------------------
template <bool EPI>
__global__ __launch_bounds__(256) void aggregate_kernel(const float* __restrict__ x,
                                                        const float* __restrict__ onorm,
                                                        const float* __restrict__ inorm,
                                                        const float* __restrict__ bias,
                                                        const int* __restrict__ rp,
                                                        const int* __restrict__ srcs,
                                                        float* __restrict__ agg, int n_nodes) {
    const int node = blockIdx.x * 4 + (threadIdx.x >> 6);
    const int lane = threadIdx.x & 63;
    const int eh = lane >> 5;       // which of the 2 edges this half-wave loads
    const int c4 = lane & 31;       // float4 column within the row
    if (node >= n_nodes) return;
    const int e0 = rp[node];
    const int e1 = rp[node + 1];
    const float4* __restrict__ x4 = (const float4*)x;

    float4 a0 = make_float4(0.f, 0.f, 0.f, 0.f);
    float4 a1 = make_float4(0.f, 0.f, 0.f, 0.f);
    float4 a2 = make_float4(0.f, 0.f, 0.f, 0.f);
    float4 a3 = make_float4(0.f, 0.f, 0.f, 0.f);

    int e = e0;
    // main: 8 edges per iteration (4 load instrs, 2 edges each)
    for (; e + 8 <= e1; e += 8) {
        const int s0 = srcs[e + 0 + eh];
        const int s1 = srcs[e + 2 + eh];
        const int s2 = srcs[e + 4 + eh];
        const int s3 = srcs[e + 6 + eh];
        const float4 v0 = x4[(size_t)s0 * 32 + c4];
        const float4 v1 = x4[(size_t)s1 * 32 + c4];
        const float4 v2 = x4[(size_t)s2 * 32 + c4];
        const float4 v3 = x4[(size_t)s3 * 32 + c4];
        a0.x += v0.x; a0.y += v0.y; a0.z += v0.z; a0.w += v0.w;
        a1.x += v1.x; a1.y += v1.y; a1.z += v1.z; a1.w += v1.w;
        a2.x += v2.x; a2.y += v2.y; a2.z += v2.z; a2.w += v2.w;
        a3.x += v3.x; a3.y += v3.y; a3.z += v3.z; a3.w += v3.w;
    }
    // tail: 2 edges per step
    for (; e + 2 <= e1; e += 2) {
        const int s0 = srcs[e + eh];
        const float4 v0 = x4[(size_t)s0 * 32 + c4];
        a0.x += v0.x; a0.y += v0.y; a0.z += v0.z; a0.w += v0.w;
    }
    // odd final edge: only half-wave eh==0 participates
    if (e < e1 && eh == 0) {
        const int s0 = srcs[e];
        const float4 v0 = x4[(size_t)s0 * 32 + c4];
        a1.x += v0.x; a1.y += v0.y; a1.z += v0.z; a1.w += v0.w;
    }

    float4 r;
    r.x = (a0.x + a1.x) + (a2.x + a3.x);
    r.y = (a0.y + a1.y) + (a2.y + a3.y);
    r.z = (a0.z + a1.z) + (a2.z + a3.z);
    r.w = (a0.w + a1.w) + (a2.w + a3.w);
    // merge the two edge-halves (lanes L and L^32 hold the same columns)
    r.x += __shfl_xor(r.x, 32, 64);
    r.y += __shfl_xor(r.y, 32, 64);
    r.z += __shfl_xor(r.z, 32, 64);
    r.w += __shfl_xor(r.w, 32, 64);

    if (eh == 0) {
        if (EPI) {
            const float inm = inorm[node];
            const float onm = onorm[node];
            const float4 bv = ((const float4*)bias)[c4];
            r.x = fmaxf(fmaf(r.x, inm, bv.x), 0.f) * onm;
            r.y = fmaxf(fmaf(r.y, inm, bv.y), 0.f) * onm;
            r.z = fmaxf(fmaf(r.z, inm, bv.z), 0.f) * onm;
            r.w = fmaxf(fmaf(r.w, inm, bv.w), 0.f) * onm;
        }
        ((float4*)(agg + (size_t)node * D))[c4] = r;
    }
}

// ---------------------------------------------------------------------------
// LDS GEMM + configurable epilogue (R2-proven inner loop).
// FULL:  multiply by inorm[row] and add bias   (layers 2,3 post-aggregate)
// RELU:  clamp at 0                            (layers 1,2)
// OSCALE: multiply by onorm[row]               (prescale for next aggregate;
//         on GEMM1 this is the ONLY epilogue -> aggregates never load onorm)
// ---------------------------------------------------------------------------
template <bool FULL, bool RELU, bool OSCALE>
__global__ __launch_bounds__(256) void gemm_epi_kernel(const float* __restrict__ A,
                                                       const float* __restrict__ W,
                                                       const float* __restrict__ b,
                                                       const float* __restrict__ inorm,
                                                       const float* __restrict__ onorm,
                                                       float* __restrict__ out, int nrows) {
    __shared__ float sW[D * D];        // 64 KB
    __shared__ float sA[128 * 132];    // 66 KB
    const int t = threadIdx.x;
    const int tc = t & 15;
    const int tr = t >> 4;

    for (int i = t; i < D * D / 4; i += 256)
        ((float4*)sW)[i] = ((const float4*)W)[i];

    const int row0 = blockIdx.x * 128;
    const int rows = min(128, nrows - row0);

    for (int i = t; i < rows * 32; i += 256) {
        const int r = i >> 5;
        const int k4 = i & 31;
        *(float4*)&sA[r * 132 + k4 * 4] = ((const float4*)(A + (size_t)(row0 + r) * D))[k4];
    }
    __syncthreads();

    float acc[8][8];
#pragma unroll
    for (int i = 0; i < 8; ++i)
#pragma unroll
        for (int j = 0; j < 8; ++j) acc[i][j] = 0.f;

    for (int k4 = 0; k4 < 32; ++k4) {
        float4 a4[8];
#pragma unroll
        for (int i = 0; i < 8; ++i)
            a4[i] = *(const float4*)&sA[(tr * 8 + i) * 132 + k4 * 4];
#pragma unroll
        for (int kk = 0; kk < 4; ++kk) {
            const float4 wlo = *(const float4*)&sW[(k4 * 4 + kk) * D + tc * 8];
            const float4 whi = *(const float4*)&sW[(k4 * 4 + kk) * D + tc * 8 + 4];
#pragma unroll
            for (int i = 0; i < 8; ++i) {
                const float av = ((const float*)&a4[i])[kk];
                acc[i][0] = fmaf(av, wlo.x, acc[i][0]);
                acc[i][1] = fmaf(av, wlo.y, acc[i][1]);
                acc[i][2] = fmaf(av, wlo.z, acc[i][2]);
                acc[i][3] = fmaf(av, wlo.w, acc[i][3]);
                acc[i][4] = fmaf(av, whi.x, acc[i][4]);
                acc[i][5] = fmaf(av, whi.y, acc[i][5]);
                acc[i][6] = fmaf(av, whi.z, acc[i][6]);
                acc[i][7] = fmaf(av, whi.w, acc[i][7]);
            }
        }
    }

#pragma unroll
    for (int i = 0; i < 8; ++i) {
        const int r = tr * 8 + i;
        if (r < rows) {
            float4 o0 = make_float4(acc[i][0], acc[i][1], acc[i][2], acc[i][3]);
            float4 o1 = make_float4(acc[i][4], acc[i][5], acc[i][6], acc[i][7]);
            if (FULL) {
                const float nm = inorm[row0 + r];
                const float4 bv0 = *(const float4*)&b[tc * 8];
                const float4 bv1 = *(const float4*)&b[tc * 8 + 4];
                o0.x = fmaf(o0.x, nm, bv0.x); o0.y = fmaf(o0.y, nm, bv0.y);
                o0.z = fmaf(o0.z, nm, bv0.z); o0.w = fmaf(o0.w, nm, bv0.w);
                o1.x = fmaf(o1.x, nm, bv1.x); o1.y = fmaf(o1.y, nm, bv1.y);
                o1.z = fmaf(o1.z, nm, bv1.z); o1.w = fmaf(o1.w, nm, bv1.w);
            }
            if (RELU) {
                o0.x = fmaxf(o0.x, 0.f); o0.y = fmaxf(o0.y, 0.f);
                o0.z = fmaxf(o0.z, 0.f); o0.w = fmaxf(o0.w, 0.f);
                o1.x = fmaxf(o1.x, 0.f); o1.y = fmaxf(o1.y, 0.f);
                o1.z = fmaxf(o1.z, 0.f); o1.w = fmaxf(o1.w, 0.f);
            }
            if (OSCALE) {
                const float os = onorm[row0 + r];
                o0.x *= os; o0.y *= os; o0.z *= os; o0.w *= os;
                o1.x *= os; o1.y *= os; o1.z *= os; o1.w *= os;
            }
            float* op = &out[(size_t)(row0 + r) * D + tc * 8];
            *(float4*)op = o0;
            *(float4*)(op + 4) = o1;
        }
    }
}

// ---------------------------------------------------------------------------
// Host launch
// ---------------------------------------------------------------------------
extern "C" void kernel_launch(void* const* d_in, const int* in_sizes, int n_in,
                              void* d_out, int out_size, void* d_ws, size_t ws_size,
                              hipStream_t stream) {
    const float* x   = (const float*)d_in[0];
    const int*   src = (const int*)d_in[1];
    const int*   dst = (const int*)d_in[2];
    const float* W1  = (const float*)d_in[3];
    const float* b1  = (const float*)d_in[4];
    const float* W2  = (const float*)d_in[5];
    const float* b2  = (const float*)d_in[6];
    const float* W3  = (const float*)d_in[7];
    const float* b3  = (const float*)d_in[8];

    const int N = in_sizes[0] / D;   // 50000
    const int E = in_sizes[1];       // 800000

    char* p = (char*)d_ws;
    auto alloc = [&](size_t bytes) -> void* {
        void* r = (void*)p;
        p += (bytes + 255) & ~(size_t)255;
        return r;
    };
    int*   cnt_out = (int*)alloc((size_t)N * 4);
    int*   cnt_in  = (int*)alloc((size_t)N * 4);
    int*   rp      = (int*)alloc((size_t)(N + 1) * 4);
    int*   rank    = (int*)alloc((size_t)E * 4);
    int*   bsum    = (int*)alloc(1024 * 4);
    float* onorm   = (float*)alloc((size_t)N * 4);
    float* inorm   = (float*)alloc((size_t)N * 4);
    int*   srcs    = (int*)alloc((size_t)E * 4);
    float* bufA    = (float*)alloc((size_t)N * D * 4);
    float* bufB    = (float*)alloc((size_t)N * D * 4);
    float* outf    = (float*)d_out;

    hipMemsetAsync(cnt_out, 0, (size_t)((char*)cnt_in - (char*)cnt_out) + (size_t)N * 4, stream);

    const int nb = (N + 1023) / 1024;
    const int gemmGrid = (N + 127) / 128;
    const int edgeGrid = (E + 255) / 256;
    const int aggGrid = (N + 3) / 4;           // wave-per-node, 4 nodes/block

    // Graph build
    count_deg_kernel<<<edgeGrid, 256, 0, stream>>>(src, dst, cnt_out, cnt_in, rank, E);
    scan_block_kernel<<<nb, 1024, 0, stream>>>(cnt_in, rp, bsum, N);
    scan_partials_kernel<<<1, 64, 0, stream>>>(bsum, &rp[N], nb);
    finalize_kernel<<<nb, 1024, 0, stream>>>(rp, bsum, cnt_out, cnt_in, onorm, inorm, N);
    fill_csr_kernel<<<edgeGrid, 256, 0, stream>>>(src, dst, rank, rp, srcs, E);

    // Layer 1: y1 = (x@W1)*onorm  (graph-independent; prescale kills per-edge
    // onorm loads in ALL aggregates), then aggregate with full fused epilogue.
    gemm_epi_kernel<false, false, true><<<gemmGrid, 256, 0, stream>>>(
        x, W1, b1, inorm, onorm, bufA, N);
    aggregate_kernel<true><<<aggGrid, 256, 0, stream>>>(
        bufA, onorm, inorm, b1, rp, srcs, bufB, N);
    // Layer 2
    aggregate_kernel<false><<<aggGrid, 256, 0, stream>>>(
        bufB, onorm, inorm, b2, rp, srcs, bufA, N);
    gemm_epi_kernel<true, true, true><<<gemmGrid, 256, 0, stream>>>(
        bufA, W2, b2, inorm, onorm, bufB, N);
    // Layer 3
    aggregate_kernel<false><<<aggGrid, 256, 0, stream>>>(
        bufB, onorm, inorm, b3, rp, srcs, bufA, N);
    gemm_epi_kernel<true, false, false><<<gemmGrid, 256, 0, stream>>>(
        bufA, W3, b3, inorm, onorm, outf, N);
}

// Round 6
// 418.866 us; speedup vs baseline: 1.3672x; 1.1693x over previous
//
#include <hip/hip_runtime.h>
#include <hip/hip_fp16.h>

#define D 128

// 8-byte vector of 4 halves (one lane's slice of a 256B fp16 row)
struct H4 { __half2 a, b; };

// ---------------------------------------------------------------------------
// Degree counting + rank capture (standalone — R4 proved fusing GEMM work in
// starves the atomic pipeline of resident waves: 139us fused vs 74us alone).
// Memory-side RMW bound: 1.6M atomics = 52.9MB WRITE @ ~670GB/s -> ~79us.
// ---------------------------------------------------------------------------
__global__ void count_deg_kernel(const int* __restrict__ src, const int* __restrict__ dst,
                                 int* __restrict__ cnt_out, int* __restrict__ cnt_in,
                                 int* __restrict__ rank, int nE) {
    int e = blockIdx.x * 256 + threadIdx.x;
    if (e < nE) {
        atomicAdd(&cnt_out[src[e]], 1);
        rank[e] = atomicAdd(&cnt_in[dst[e]], 1);
    }
}

// ---------------------------------------------------------------------------
// Multi-block exclusive scan, stage 1.
// ---------------------------------------------------------------------------
__global__ __launch_bounds__(1024) void scan_block_kernel(const int* __restrict__ deg,
                                                          int* __restrict__ rp,
                                                          int* __restrict__ bsum, int n) {
    __shared__ int wsum[16];
    const int t = threadIdx.x;
    const int lane = t & 63;
    const int wid = t >> 6;
    const int i = blockIdx.x * 1024 + t;
    const int v = (i < n) ? deg[i] : 0;
    int s = v;
#pragma unroll
    for (int off = 1; off < 64; off <<= 1) {
        int u = __shfl_up(s, off, 64);
        if (lane >= off) s += u;
    }
    if (lane == 63) wsum[wid] = s;
    __syncthreads();
    if (wid == 0) {
        int ws = (lane < 16) ? wsum[lane] : 0;
#pragma unroll
        for (int off = 1; off < 16; off <<= 1) {
            int u = __shfl_up(ws, off, 64);
            if (lane >= off) ws += u;
        }
        if (lane < 16) wsum[lane] = ws;
    }
    __syncthreads();
    const int excl = s - v + ((wid > 0) ? wsum[wid - 1] : 0);
    if (i < n) rp[i] = excl;
    if (t == 0) bsum[blockIdx.x] = wsum[15];
}

__global__ void scan_partials_kernel(int* __restrict__ bsum, int* __restrict__ rp_total, int nb) {
    const int lane = threadIdx.x;  // 64
    int carry = 0;
    for (int base = 0; base < nb; base += 64) {
        const int i = base + lane;
        const int v = (i < nb) ? bsum[i] : 0;
        int s = v;
#pragma unroll
        for (int off = 1; off < 64; off <<= 1) {
            int u = __shfl_up(s, off, 64);
            if (lane >= off) s += u;
        }
        if (i < nb) bsum[i] = s - v + carry;
        carry += __shfl(s, 63, 64);
    }
    if (lane == 0) rp_total[0] = carry;
}

__global__ __launch_bounds__(1024) void finalize_kernel(int* __restrict__ rp,
                                                        const int* __restrict__ bsum,
                                                        const int* __restrict__ cnt_out,
                                                        const int* __restrict__ cnt_in,
                                                        float* __restrict__ onorm,
                                                        float* __restrict__ inorm, int n) {
    const int i = blockIdx.x * 1024 + threadIdx.x;
    if (i < n) {
        rp[i] += bsum[blockIdx.x];
        onorm[i] = rsqrtf(fmaxf((float)cnt_out[i], 1.0f));
        inorm[i] = rsqrtf(fmaxf((float)cnt_in[i], 1.0f));
    }
}

__global__ void fill_csr_kernel(const int* __restrict__ src, const int* __restrict__ dst,
                                const int* __restrict__ rank, const int* __restrict__ rp,
                                int* __restrict__ srcs_sorted, int nE) {
    int e = blockIdx.x * 256 + threadIdx.x;
    if (e < nE) {
        srcs_sorted[rp[dst[e]] + rank[e]] = src[e];
    }
}

// ---------------------------------------------------------------------------
// Aggregation, wave-per-node, FP16 GATHER: agg[n,:] = sum_{e: dst==n} x[src_e,:]
// R5 showed the fp32 gather is memory-system-BW-bound (~5.5 TB/s on 410MB of
// random 512B rows; instruction-level restructuring was neutral). fp16 rows
// halve the bytes: 256B/edge. Accumulation is fp32 (converted on load).
// Inputs are always onorm-prescaled by the producing epilogue.
// EPI (layer 1): out = relu(r*inorm[n] + b)*onorm[n], written fp16 (feeds the
// next gather). Non-EPI: raw sum written fp32 (feeds a GEMM).
// ---------------------------------------------------------------------------
template <bool EPI>
__global__ __launch_bounds__(256) void aggregate_kernel(const __half* __restrict__ xh,
                                                        const float* __restrict__ onorm,
                                                        const float* __restrict__ inorm,
                                                        const float* __restrict__ bias,
                                                        const int* __restrict__ rp,
                                                        const int* __restrict__ srcs,
                                                        void* __restrict__ aggv, int n_nodes) {
    const int node = blockIdx.x * 4 + (threadIdx.x >> 6);
    const int lane = threadIdx.x & 63;
    const int eh = lane >> 5;       // which of the 2 edges this half-wave loads
    const int c4 = lane & 31;       // H4 column within the 128-half row
    if (node >= n_nodes) return;
    const int e0 = rp[node];
    const int e1 = rp[node + 1];

    float4 a0 = make_float4(0.f, 0.f, 0.f, 0.f);
    float4 a1 = make_float4(0.f, 0.f, 0.f, 0.f);
    float4 a2 = make_float4(0.f, 0.f, 0.f, 0.f);
    float4 a3 = make_float4(0.f, 0.f, 0.f, 0.f);

    auto accum = [&](float4& acc, const H4 v) {
        acc.x += __low2float(v.a);  acc.y += __high2float(v.a);
        acc.z += __low2float(v.b);  acc.w += __high2float(v.b);
    };

    int e = e0;
    // main: 8 edges per iteration (4 load instrs, 2 edges each, 8B/lane)
    for (; e + 8 <= e1; e += 8) {
        const int s0 = srcs[e + 0 + eh];
        const int s1 = srcs[e + 2 + eh];
        const int s2 = srcs[e + 4 + eh];
        const int s3 = srcs[e + 6 + eh];
        const H4 v0 = ((const H4*)(xh + (size_t)s0 * D))[c4];
        const H4 v1 = ((const H4*)(xh + (size_t)s1 * D))[c4];
        const H4 v2 = ((const H4*)(xh + (size_t)s2 * D))[c4];
        const H4 v3 = ((const H4*)(xh + (size_t)s3 * D))[c4];
        accum(a0, v0); accum(a1, v1); accum(a2, v2); accum(a3, v3);
    }
    for (; e + 2 <= e1; e += 2) {
        const int s0 = srcs[e + eh];
        accum(a0, ((const H4*)(xh + (size_t)s0 * D))[c4]);
    }
    if (e < e1 && eh == 0) {
        const int s0 = srcs[e];
        accum(a1, ((const H4*)(xh + (size_t)s0 * D))[c4]);
    }

    float4 r;
    r.x = (a0.x + a1.x) + (a2.x + a3.x);
    r.y = (a0.y + a1.y) + (a2.y + a3.y);
    r.z = (a0.z + a1.z) + (a2.z + a3.z);
    r.w = (a0.w + a1.w) + (a2.w + a3.w);
    r.x += __shfl_xor(r.x, 32, 64);
    r.y += __shfl_xor(r.y, 32, 64);
    r.z += __shfl_xor(r.z, 32, 64);
    r.w += __shfl_xor(r.w, 32, 64);

    if (eh == 0) {
        if (EPI) {
            const float inm = inorm[node];
            const float onm = onorm[node];
            const float4 bv = ((const float4*)bias)[c4];
            r.x = fmaxf(fmaf(r.x, inm, bv.x), 0.f) * onm;
            r.y = fmaxf(fmaf(r.y, inm, bv.y), 0.f) * onm;
            r.z = fmaxf(fmaf(r.z, inm, bv.z), 0.f) * onm;
            r.w = fmaxf(fmaf(r.w, inm, bv.w), 0.f) * onm;
            H4 h;
            h.a = __floats2half2_rn(r.x, r.y);
            h.b = __floats2half2_rn(r.z, r.w);
            ((H4*)((__half*)aggv + (size_t)node * D))[c4] = h;
        } else {
            ((float4*)((float*)aggv + (size_t)node * D))[c4] = r;
        }
    }
}

// ---------------------------------------------------------------------------
// LDS GEMM + configurable epilogue (R2-proven inner loop; fp32 A input).
// FULL:   *inorm[row] + bias       (layers 2,3: input came from an aggregate)
// RELU:   clamp at 0               (layers 1,2)
// OSCALE: *onorm[row]              (prescale for the next gather)
// OUT16:  emit fp16 (the buffer feeds a gather; halves that kernel's traffic)
// ---------------------------------------------------------------------------
template <bool FULL, bool RELU, bool OSCALE, bool OUT16>
__global__ __launch_bounds__(256) void gemm_epi_kernel(const float* __restrict__ A,
                                                       const float* __restrict__ W,
                                                       const float* __restrict__ b,
                                                       const float* __restrict__ inorm,
                                                       const float* __restrict__ onorm,
                                                       void* __restrict__ outv, int nrows) {
    __shared__ float sW[D * D];        // 64 KB
    __shared__ float sA[128 * 132];    // 66 KB
    const int t = threadIdx.x;
    const int tc = t & 15;
    const int tr = t >> 4;

    for (int i = t; i < D * D / 4; i += 256)
        ((float4*)sW)[i] = ((const float4*)W)[i];

    const int row0 = blockIdx.x * 128;
    const int rows = min(128, nrows - row0);

    for (int i = t; i < rows * 32; i += 256) {
        const int r = i >> 5;
        const int k4 = i & 31;
        *(float4*)&sA[r * 132 + k4 * 4] = ((const float4*)(A + (size_t)(row0 + r) * D))[k4];
    }
    __syncthreads();

    float acc[8][8];
#pragma unroll
    for (int i = 0; i < 8; ++i)
#pragma unroll
        for (int j = 0; j < 8; ++j) acc[i][j] = 0.f;

    for (int k4 = 0; k4 < 32; ++k4) {
        float4 a4[8];
#pragma unroll
        for (int i = 0; i < 8; ++i)
            a4[i] = *(const float4*)&sA[(tr * 8 + i) * 132 + k4 * 4];
#pragma unroll
        for (int kk = 0; kk < 4; ++kk) {
            const float4 wlo = *(const float4*)&sW[(k4 * 4 + kk) * D + tc * 8];
            const float4 whi = *(const float4*)&sW[(k4 * 4 + kk) * D + tc * 8 + 4];
#pragma unroll
            for (int i = 0; i < 8; ++i) {
                const float av = ((const float*)&a4[i])[kk];
                acc[i][0] = fmaf(av, wlo.x, acc[i][0]);
                acc[i][1] = fmaf(av, wlo.y, acc[i][1]);
                acc[i][2] = fmaf(av, wlo.z, acc[i][2]);
                acc[i][3] = fmaf(av, wlo.w, acc[i][3]);
                acc[i][4] = fmaf(av, whi.x, acc[i][4]);
                acc[i][5] = fmaf(av, whi.y, acc[i][5]);
                acc[i][6] = fmaf(av, whi.z, acc[i][6]);
                acc[i][7] = fmaf(av, whi.w, acc[i][7]);
            }
        }
    }

#pragma unroll
    for (int i = 0; i < 8; ++i) {
        const int r = tr * 8 + i;
        if (r < rows) {
            float4 o0 = make_float4(acc[i][0], acc[i][1], acc[i][2], acc[i][3]);
            float4 o1 = make_float4(acc[i][4], acc[i][5], acc[i][6], acc[i][7]);
            if (FULL) {
                const float nm = inorm[row0 + r];
                const float4 bv0 = *(const float4*)&b[tc * 8];
                const float4 bv1 = *(const float4*)&b[tc * 8 + 4];
                o0.x = fmaf(o0.x, nm, bv0.x); o0.y = fmaf(o0.y, nm, bv0.y);
                o0.z = fmaf(o0.z, nm, bv0.z); o0.w = fmaf(o0.w, nm, bv0.w);
                o1.x = fmaf(o1.x, nm, bv1.x); o1.y = fmaf(o1.y, nm, bv1.y);
                o1.z = fmaf(o1.z, nm, bv1.z); o1.w = fmaf(o1.w, nm, bv1.w);
            }
            if (RELU) {
                o0.x = fmaxf(o0.x, 0.f); o0.y = fmaxf(o0.y, 0.f);
                o0.z = fmaxf(o0.z, 0.f); o0.w = fmaxf(o0.w, 0.f);
                o1.x = fmaxf(o1.x, 0.f); o1.y = fmaxf(o1.y, 0.f);
                o1.z = fmaxf(o1.z, 0.f); o1.w = fmaxf(o1.w, 0.f);
            }
            if (OSCALE) {
                const float os = onorm[row0 + r];
                o0.x *= os; o0.y *= os; o0.z *= os; o0.w *= os;
                o1.x *= os; o1.y *= os; o1.z *= os; o1.w *= os;
            }
            if (OUT16) {
                __half2 h[4];
                h[0] = __floats2half2_rn(o0.x, o0.y);
                h[1] = __floats2half2_rn(o0.z, o0.w);
                h[2] = __floats2half2_rn(o1.x, o1.y);
                h[3] = __floats2half2_rn(o1.z, o1.w);
                *(float4*)((__half*)outv + (size_t)(row0 + r) * D + tc * 8) = *(float4*)h;
            } else {
                float* op = (float*)outv + (size_t)(row0 + r) * D + tc * 8;
                *(float4*)op = o0;
                *(float4*)(op + 4) = o1;
            }
        }
    }
}

// ---------------------------------------------------------------------------
// Host launch
// ---------------------------------------------------------------------------
extern "C" void kernel_launch(void* const* d_in, const int* in_sizes, int n_in,
                              void* d_out, int out_size, void* d_ws, size_t ws_size,
                              hipStream_t stream) {
    const float* x   = (const float*)d_in[0];
    const int*   src = (const int*)d_in[1];
    const int*   dst = (const int*)d_in[2];
    const float* W1  = (const float*)d_in[3];
    const float* b1  = (const float*)d_in[4];
    const float* W2  = (const float*)d_in[5];
    const float* b2  = (const float*)d_in[6];
    const float* W3  = (const float*)d_in[7];
    const float* b3  = (const float*)d_in[8];

    const int N = in_sizes[0] / D;   // 50000
    const int E = in_sizes[1];       // 800000

    char* p = (char*)d_ws;
    auto alloc = [&](size_t bytes) -> void* {
        void* r = (void*)p;
        p += (bytes + 255) & ~(size_t)255;
        return r;
    };
    int*    cnt_out = (int*)alloc((size_t)N * 4);
    int*    cnt_in  = (int*)alloc((size_t)N * 4);
    int*    rp      = (int*)alloc((size_t)(N + 1) * 4);
    int*    rank    = (int*)alloc((size_t)E * 4);
    int*    bsum    = (int*)alloc(1024 * 4);
    float*  onorm   = (float*)alloc((size_t)N * 4);
    float*  inorm   = (float*)alloc((size_t)N * 4);
    int*    srcs    = (int*)alloc((size_t)E * 4);
    __half* hbuf0   = (__half*)alloc((size_t)N * D * 2);  // y1, then h2
    __half* hbuf1   = (__half*)alloc((size_t)N * D * 2);  // h1
    float*  abuf    = (float*)alloc((size_t)N * D * 4);   // a2, a3
    float*  outf    = (float*)d_out;

    hipMemsetAsync(cnt_out, 0, (size_t)((char*)cnt_in - (char*)cnt_out) + (size_t)N * 4, stream);

    const int nb = (N + 1023) / 1024;
    const int gemmGrid = (N + 127) / 128;
    const int edgeGrid = (E + 255) / 256;
    const int aggGrid = (N + 3) / 4;

    // Graph build
    count_deg_kernel<<<edgeGrid, 256, 0, stream>>>(src, dst, cnt_out, cnt_in, rank, E);
    scan_block_kernel<<<nb, 1024, 0, stream>>>(cnt_in, rp, bsum, N);
    scan_partials_kernel<<<1, 64, 0, stream>>>(bsum, &rp[N], nb);
    finalize_kernel<<<nb, 1024, 0, stream>>>(rp, bsum, cnt_out, cnt_in, onorm, inorm, N);
    fill_csr_kernel<<<edgeGrid, 256, 0, stream>>>(src, dst, rank, rp, srcs, E);

    // Layer 1: y1 = (x@W1)*onorm -> fp16; aggregate+epilogue -> h1 fp16
    gemm_epi_kernel<false, false, true, true><<<gemmGrid, 256, 0, stream>>>(
        x, W1, b1, inorm, onorm, hbuf0, N);
    aggregate_kernel<true><<<aggGrid, 256, 0, stream>>>(
        hbuf0, onorm, inorm, b1, rp, srcs, hbuf1, N);
    // Layer 2: a2 = agg(h1) fp32; h2 = relu((a2@W2)*inorm+b2)*onorm -> fp16
    aggregate_kernel<false><<<aggGrid, 256, 0, stream>>>(
        hbuf1, onorm, inorm, b2, rp, srcs, abuf, N);
    gemm_epi_kernel<true, true, true, true><<<gemmGrid, 256, 0, stream>>>(
        abuf, W2, b2, inorm, onorm, hbuf0, N);
    // Layer 3: a3 = agg(h2) fp32; out = (a3@W3)*inorm+b3 fp32
    aggregate_kernel<false><<<aggGrid, 256, 0, stream>>>(
        hbuf0, onorm, inorm, b3, rp, srcs, abuf, N);
    gemm_epi_kernel<true, false, false, false><<<gemmGrid, 256, 0, stream>>>(
        abuf, W3, b3, inorm, onorm, outf, N);
}